// Round 17
// baseline (536.519 us; speedup 1.0000x reference)
//
#include <hip/hip_runtime.h>
#include <hip/hip_fp16.h>

#define N_NODES 50000
#define N_FEAT  128
#define HID     64
#define N_EDGES 800000
#define N_GRAPHS 64
#define MAXDEG  64
#define BN_EPS  1e-5f
#define NB256(n) (((n) + 255) / 256)

// ---------------- zero fill counters ----------------
__global__ __launch_bounds__(256) void k_zero(int* fill) {
    int i = blockIdx.x * 256 + threadIdx.x;
    if (i < N_NODES) fill[i] = 0;
}

// ---- GEMM body: 40 nodes/block, x staged fully, W chunk-staged (16 f4-k) ----
template <int K, bool HOUT>
__device__ __forceinline__ void gemm_body(int vb,
                                          const float* __restrict__ in,
                                          const float* __restrict__ W,
                                          float* __restrict__ outf,
                                          __half* __restrict__ outh,
                                          float4* Wt, float4* xs) {
    constexpr int K4 = K / 4;
    const int t = threadIdx.x;
    const int base = vb * 40;

    const float4* xv = (const float4*)(in + (long long)base * K);
    for (int i = t; i < 40 * K4; i += 256) xs[i] = xv[i];

    const float4* Wv = (const float4*)W;
    const int hh = t & 63;
    const int ng = t >> 6;
    float4 acc[10];
#pragma unroll
    for (int j = 0; j < 10; ++j) acc[j] = make_float4(0.f, 0.f, 0.f, 0.f);

    for (int c = 0; c < K4; c += 16) {
        __syncthreads();  // WAR on Wt (also orders xs staging before first MAC)
        for (int i = t; i < HID * 16; i += 256) {
            int h2 = i >> 4, k4 = i & 15;
            Wt[k4 * 65 + h2] = Wv[h2 * K4 + c + k4];
        }
        __syncthreads();
#pragma unroll
        for (int k4 = 0; k4 < 16; ++k4) {
            float4 w = Wt[k4 * 65 + hh];
#pragma unroll
            for (int j = 0; j < 10; ++j) {
                float4 x = xs[(ng + 4 * j) * K4 + c + k4];
                acc[j].x += w.x * x.x;
                acc[j].y += w.y * x.y;
                acc[j].z += w.z * x.z;
                acc[j].w += w.w * x.w;
            }
        }
    }
#pragma unroll
    for (int j = 0; j < 10; ++j) {
        int node = base + ng + 4 * j;
        float v = acc[j].x + acc[j].y + acc[j].z + acc[j].w;
        if (HOUT) outh[node * HID + hh] = __float2half(v);
        else      outf[node * HID + hh] = v;
    }
}

// ---------------- GEMMs with piggybacked edge placement ----------------
#define GE_NB 2500
__global__ __launch_bounds__(256) void k_gemmedge(const int* __restrict__ ei,
                                                  int* fill, unsigned short* __restrict__ colp,
                                                  const float* __restrict__ x,
                                                  const float* __restrict__ W_in,
                                                  const float* __restrict__ W1,
                                                  float* __restrict__ h,
                                                  __half* __restrict__ g16) {
    __shared__ float4 Wt[16 * 65];
    __shared__ float4 xs[40 * 32];
    const int bid = blockIdx.x;
    const int t = threadIdx.x;

    // edge slice: issue atomics now, consume results after the GEMM
    const int ebase = bid * 320;
    int s1 = ei[ebase + t];
    int d1 = ei[N_EDGES + ebase + t];
    int k1 = atomicAdd(&fill[d1], 1);
    int s2 = 0, d2 = 0, k2 = MAXDEG;
    if (t < 64) {
        s2 = ei[ebase + 256 + t];
        d2 = ei[N_EDGES + ebase + 256 + t];
        k2 = atomicAdd(&fill[d2], 1);
    }

    if (bid < 1250)
        gemm_body<N_FEAT, false>(bid, x, W_in, h, nullptr, Wt, xs);
    else
        gemm_body<N_FEAT, true>(bid - 1250, x, W1, nullptr, g16, Wt, xs);

    // deferred stores: atomic results long since returned
    if (k1 < MAXDEG) colp[d1 * MAXDEG + k1] = (unsigned short)s1;
    if (k2 < MAXDEG) colp[d2 * MAXDEG + k2] = (unsigned short)s2;
}

// ---- fp16 row accumulate, scaled (FMA — same cost as plain add) ----
__device__ __forceinline__ void acc8s(const uint4 r, float* a, float s) {
    float2 f0 = __half22float2(*(const __half2*)&r.x);
    float2 f1 = __half22float2(*(const __half2*)&r.y);
    float2 f2 = __half22float2(*(const __half2*)&r.z);
    float2 f3 = __half22float2(*(const __half2*)&r.w);
    a[0] += s * f0.x; a[1] += s * f0.y; a[2] += s * f1.x; a[3] += s * f1.y;
    a[4] += s * f2.x; a[5] += s * f2.y; a[6] += s * f3.x; a[7] += s * f3.y;
}

// ------ fused gather(+BN/ReLU/res) [+ per-wave GEMM], FOUR nodes per wave ------
// 3125 blocks, 16 nodes/block, 4 independent gather chains per wave (32
// outstanding row loads per wave slot). Two col-prefetch registers keep each
// node's 32-slot coverage (deg>32 tail stays rare). BN params folded to 16
// regs: val = a*(di*sc) + base, sc = g*rsqrt(v+eps), base = (b-m)*sc + e.
template <bool NSCALE, bool DOGEMM>
__global__ __launch_bounds__(256) void k_gather_fused(const __half* __restrict__ gin,
                                                      const unsigned short* __restrict__ colp,
                                                      const int* __restrict__ fill,
                                                      const float* __restrict__ b,
                                                      const float* __restrict__ gamma,
                                                      const float* __restrict__ beta,
                                                      const float* __restrict__ mean,
                                                      const float* __restrict__ var,
                                                      const float4* __restrict__ res4,
                                                      float4* __restrict__ h4,
                                                      const float* __restrict__ W,
                                                      __half* __restrict__ gout) {
    __shared__ float4 Wt[DOGEMM ? 16 * 65 : 1];
    __shared__ float4 hrow[DOGEMM ? 16 * 16 : 1];

    const int t = threadIdx.x;
    const int wv = t >> 6;
    const int lane = t & 63;
    const int hh8 = lane & 7;
    const int sub = lane >> 3;
    const int nbase = blockIdx.x * 16 + wv * 4;

    if (DOGEMM) {
        const float4* Wv = (const float4*)W;
        for (int i = t; i < HID * 16; i += 256) {
            int h2 = i >> 4, k4 = i & 15;
            Wt[k4 * 65 + h2] = Wv[i];
        }
        __syncthreads();   // only block barrier: Wt visible before any use
    }

    const uint4* gv = (const uint4*)gin;  // row = 8 x uint4 (128 B)
    int fls[4], degs[4];
#pragma unroll
    for (int i = 0; i < 4; ++i) {
        fls[i] = fill[nbase + i];
        degs[i] = fls[i] < MAXDEG ? fls[i] : MAXDEG;
    }

    // col prefetch: call01 covers nodes 0/1 (lanes 0-31 / 32-63), call23 -> 2/3
    const int half = lane >> 5;
    const int myj = lane & 31;
    const int n01 = nbase + half,     n23 = nbase + 2 + half;
    const int dg01 = degs[half],      dg23 = degs[2 + half];
    const bool v01 = (myj < dg01),    v23 = (myj < dg23);
    int call01 = v01 ? (int)colp[n01 * MAXDEG + myj] : n01;
    int call23 = v23 ? (int)colp[n23 * MAXDEG + myj] : n23;
    float sall01, sall23;
    if (NSCALE) {
        sall01 = v01 ? rsqrtf((float)fill[call01] + 1.0f) : 0.0f;
        sall23 = v23 ? rsqrtf((float)fill[call23] + 1.0f) : 0.0f;
    } else {
        sall01 = v01 ? 1.0f : 0.0f;
        sall23 = v23 ? 1.0f : 0.0f;
    }

    float a[4][8];
#pragma unroll
    for (int i = 0; i < 4; ++i)
#pragma unroll
        for (int k = 0; k < 8; ++k) a[i][k] = 0.f;

    int nrr[4];
#pragma unroll
    for (int i = 0; i < 4; ++i) {
        int d32 = degs[i] < 32 ? degs[i] : 32;
        nrr[i] = (d32 + 7) >> 3;
    }
    int nrmax = nrr[0];
#pragma unroll
    for (int i = 1; i < 4; ++i) nrmax = nrr[i] > nrmax ? nrr[i] : nrmax;

#pragma unroll 2
    for (int r = 0; r < nrmax; ++r) {
        int j = r * 8 + sub;
        if (r < nrr[0]) { int c = __shfl(call01, j);      float s = __shfl(sall01, j);      acc8s(gv[c * 8 + hh8], a[0], s); }
        if (r < nrr[1]) { int c = __shfl(call01, 32 + j); float s = __shfl(sall01, 32 + j); acc8s(gv[c * 8 + hh8], a[1], s); }
        if (r < nrr[2]) { int c = __shfl(call23, j);      float s = __shfl(sall23, j);      acc8s(gv[c * 8 + hh8], a[2], s); }
        if (r < nrr[3]) { int c = __shfl(call23, 32 + j); float s = __shfl(sall23, 32 + j); acc8s(gv[c * 8 + hh8], a[3], s); }
    }
    // rare overflow (deg > 32): wave-uniform tails, direct colp loads
#pragma unroll
    for (int i = 0; i < 4; ++i) {
        if (degs[i] > 32) {
            int n = nbase + i;
            for (int j = 32 + sub; j < degs[i]; j += 8) {
                int c = (int)colp[n * MAXDEG + j];
                float s = NSCALE ? rsqrtf((float)fill[c] + 1.0f) : 1.0f;
                acc8s(gv[c * 8 + hh8], a[i], s);
            }
        }
    }

#pragma unroll
    for (int m = 8; m <= 32; m <<= 1) {
#pragma unroll
        for (int i = 0; i < 4; ++i)
#pragma unroll
            for (int k = 0; k < 8; ++k) a[i][k] += __shfl_xor(a[i][k], m);
    }
    // allreduce complete: every lane holds all 4 nodes' 8-feature sums

    float di[4];
#pragma unroll
    for (int i = 0; i < 4; ++i) di[i] = rsqrtf((float)fls[i] + 1.0f);
#pragma unroll
    for (int i = 0; i < 4; ++i)
        acc8s(gv[(nbase + i) * 8 + hh8], a[i], NSCALE ? di[i] : 1.0f);  // self loops

    // folded BN params: val = a*(di*sc) + base
    float sc[8], base8[8];
    {
        float4 b0 = ((const float4*)b)[hh8 * 2],     b1 = ((const float4*)b)[hh8 * 2 + 1];
        float4 g0 = ((const float4*)gamma)[hh8 * 2], g1 = ((const float4*)gamma)[hh8 * 2 + 1];
        float4 e0 = ((const float4*)beta)[hh8 * 2],  e1 = ((const float4*)beta)[hh8 * 2 + 1];
        float4 m0 = ((const float4*)mean)[hh8 * 2],  m1 = ((const float4*)mean)[hh8 * 2 + 1];
        float4 v0 = ((const float4*)var)[hh8 * 2],   v1 = ((const float4*)var)[hh8 * 2 + 1];
        float bb[8] = {b0.x, b0.y, b0.z, b0.w, b1.x, b1.y, b1.z, b1.w};
        float gg[8] = {g0.x, g0.y, g0.z, g0.w, g1.x, g1.y, g1.z, g1.w};
        float ee[8] = {e0.x, e0.y, e0.z, e0.w, e1.x, e1.y, e1.z, e1.w};
        float mm[8] = {m0.x, m0.y, m0.z, m0.w, m1.x, m1.y, m1.z, m1.w};
        float vv[8] = {v0.x, v0.y, v0.z, v0.w, v1.x, v1.y, v1.z, v1.w};
#pragma unroll
        for (int k = 0; k < 8; ++k) {
            sc[k] = gg[k] * rsqrtf(vv[k] + BN_EPS);
            base8[k] = (bb[k] - mm[k]) * sc[k] + ee[k];
        }
    }

#pragma unroll
    for (int i = 0; i < 4; ++i) {
        int n = nbase + i;
        float dsc;
        float o[8];
#pragma unroll
        for (int k = 0; k < 8; ++k) {
            dsc = di[i] * sc[k];
            o[k] = fmaxf(a[i][k] * dsc + base8[k], 0.f);
        }
        if (res4) {
            float4 r0 = res4[n * 16 + hh8 * 2];
            float4 r1 = res4[n * 16 + hh8 * 2 + 1];
            o[0] += r0.x; o[1] += r0.y; o[2] += r0.z; o[3] += r0.w;
            o[4] += r1.x; o[5] += r1.y; o[6] += r1.z; o[7] += r1.w;
        }
        float4 lo = make_float4(o[0], o[1], o[2], o[3]);
        float4 hi = make_float4(o[4], o[5], o[6], o[7]);
        if (sub == 0) {
            h4[n * 16 + hh8 * 2]     = lo;
            h4[n * 16 + hh8 * 2 + 1] = hi;
            if (DOGEMM) {
                hrow[(wv * 4 + i) * 16 + hh8 * 2]     = lo;
                hrow[(wv * 4 + i) * 16 + hh8 * 2 + 1] = hi;
            }
        }
    }

    if (DOGEMM) {
        // same-wave LDS write->read: in-order, no barrier; sequenced per node
        const int hh = lane;
#pragma unroll
        for (int i = 0; i < 4; ++i) {
            float4 acc = make_float4(0.f, 0.f, 0.f, 0.f);
#pragma unroll
            for (int k4 = 0; k4 < 16; ++k4) {
                float4 hv = hrow[(wv * 4 + i) * 16 + k4];  // wave-broadcast (free)
                float4 w = Wt[k4 * 65 + hh];
                acc.x += hv.x * w.x; acc.y += hv.y * w.y;
                acc.z += hv.z * w.z; acc.w += hv.w * w.w;
            }
            gout[(nbase + i) * HID + hh] =
                __float2half((acc.x + acc.y + acc.z + acc.w) * di[i]);
        }
    }
}

// ---------------- pool + final linear: one 1024-thread block per graph ----------------
__device__ __forceinline__ int lowerb(const int* __restrict__ b, int val) {
    int lo = 0, hi = N_NODES;
    while (lo < hi) {
        int mid = (lo + hi) >> 1;
        if (b[mid] < val) lo = mid + 1; else hi = mid;
    }
    return lo;
}

__global__ __launch_bounds__(1024) void k_poolfinal(const float* __restrict__ h,
                                                    const int* __restrict__ batch,
                                                    const float* __restrict__ lin_w,
                                                    const float* __restrict__ lin_b,
                                                    float* __restrict__ out) {
    __shared__ float red[16][HID];
    int g = blockIdx.x;
    int w = threadIdx.x >> 6;
    int hh = threadIdx.x & 63;
    int start = lowerb(batch, g);
    int end = lowerb(batch, g + 1);
    int len = end - start;
    float acc = 0.f;
    for (int n = start + w; n < end; n += 16) acc += h[n * HID + hh];
    red[w][hh] = acc;
    __syncthreads();
    if (w == 0) {
        float s = 0.f;
#pragma unroll
        for (int i = 0; i < 16; ++i) s += red[i][hh];
        float c = fmaxf((float)len, 1.0f);
        float v = (s / c) * lin_w[hh];
#pragma unroll
        for (int off = 32; off > 0; off >>= 1) v += __shfl_down(v, off);
        if (hh == 0) out[g] = v + lin_b[0];
    }
}

extern "C" void kernel_launch(void* const* d_in, const int* in_sizes, int n_in,
                              void* d_out, int out_size, void* d_ws, size_t ws_size,
                              hipStream_t stream) {
    const float* x     = (const float*)d_in[0];
    const int*   ei    = (const int*)d_in[1];
    const int*   batch = (const int*)d_in[2];
    const float* W_in  = (const float*)d_in[3];
    const float* W1    = (const float*)d_in[4];
    const float* b1    = (const float*)d_in[5];
    const float* Ws    = (const float*)d_in[6];
    const float* bs_   = (const float*)d_in[7];
    const float* bn_g  = (const float*)d_in[8];
    const float* bn_b  = (const float*)d_in[9];
    const float* bn_m  = (const float*)d_in[10];
    const float* bn_v  = (const float*)d_in[11];
    const float* lin_w = (const float*)d_in[12];
    const float* lin_b = (const float*)d_in[13];
    float* out = (float*)d_out;

    char* q = (char*)d_ws;
    int*            fill = (int*)q;             q += (size_t)50048 * 4;
    unsigned short* colp = (unsigned short*)q;  q += (size_t)N_NODES * MAXDEG * 2;
    __half*         g16a = (__half*)q;          q += (size_t)N_NODES * HID * 2;
    __half*         g16b = (__half*)q;          q += (size_t)N_NODES * HID * 2;
    float*          h    = (float*)q;           q += (size_t)N_NODES * HID * 4;

    const int NB_N   = NB256(N_NODES);
    const int NB_GA4 = N_NODES / 16;  // 3125
    float4* h4 = (float4*)h;

    // zero fill, then: (identity gemm || layer-1 gemm) with deferred-store edge placement
    k_zero<<<NB_N, 256, 0, stream>>>(fill);
    k_gemmedge<<<GE_NB, 256, 0, stream>>>(ei, fill, colp, x, W_in, W1, h, g16a);

    // layer 1: gather (per-source dinv; g16a unscaled) + fused gemm for layer 2
    k_gather_fused<true, true><<<NB_GA4, 256, 0, stream>>>(
        g16a, colp, fill, b1, bn_g, bn_b, bn_m, bn_v,
        (const float4*)h, h4, Ws + 0 * HID * HID, g16b);

    // layers 2-4: gather (pre-scaled g16) + fused gemm for next layer
    k_gather_fused<false, true><<<NB_GA4, 256, 0, stream>>>(
        g16b, colp, fill, bs_ + 0 * HID,
        bn_g + 1 * HID, bn_b + 1 * HID, bn_m + 1 * HID, bn_v + 1 * HID,
        (const float4*)h, h4, Ws + 1 * HID * HID, g16a);

    k_gather_fused<false, true><<<NB_GA4, 256, 0, stream>>>(
        g16a, colp, fill, bs_ + 1 * HID,
        bn_g + 2 * HID, bn_b + 2 * HID, bn_m + 2 * HID, bn_v + 2 * HID,
        (const float4*)h, h4, Ws + 2 * HID * HID, g16b);

    k_gather_fused<false, true><<<NB_GA4, 256, 0, stream>>>(
        g16b, colp, fill, bs_ + 2 * HID,
        bn_g + 3 * HID, bn_b + 3 * HID, bn_m + 3 * HID, bn_v + 3 * HID,
        (const float4*)h, h4, Ws + 3 * HID * HID, g16a);

    // layer 5: gather only (no residual, no next gemm)
    k_gather_fused<false, false><<<NB_GA4, 256, 0, stream>>>(
        g16a, colp, fill, bs_ + 3 * HID,
        bn_g + 4 * HID, bn_b + 4 * HID, bn_m + 4 * HID, bn_v + 4 * HID,
        nullptr, h4, nullptr, nullptr);

    // pool + final
    k_poolfinal<<<N_GRAPHS, 1024, 0, stream>>>(h, batch, lin_w, lin_b, out);
}

// Round 18
// 365.855 us; speedup vs baseline: 1.4665x; 1.4665x over previous
//
#include <hip/hip_runtime.h>
#include <hip/hip_fp16.h>

#define N_NODES 50000
#define N_FEAT  128
#define HID     64
#define N_EDGES 800000
#define N_GRAPHS 64
#define MAXDEG  64
#define BN_EPS  1e-5f
#define NB256(n) (((n) + 255) / 256)

// ---- GEMM body: 40 nodes/block, x staged fully, W chunk-staged (16 f4-k) ----
template <int K, bool HOUT>
__device__ __forceinline__ void gemm_body(int vb,
                                          const float* __restrict__ in,
                                          const float* __restrict__ W,
                                          float* __restrict__ outf,
                                          __half* __restrict__ outh,
                                          float4* Wt, float4* xs) {
    constexpr int K4 = K / 4;
    const int t = threadIdx.x;
    const int base = vb * 40;

    const float4* xv = (const float4*)(in + (long long)base * K);
    for (int i = t; i < 40 * K4; i += 256) xs[i] = xv[i];

    const float4* Wv = (const float4*)W;
    const int hh = t & 63;
    const int ng = t >> 6;
    float4 acc[10];
#pragma unroll
    for (int j = 0; j < 10; ++j) acc[j] = make_float4(0.f, 0.f, 0.f, 0.f);

    for (int c = 0; c < K4; c += 16) {
        __syncthreads();  // WAR on Wt (also orders xs staging before first MAC)
        for (int i = t; i < HID * 16; i += 256) {
            int h2 = i >> 4, k4 = i & 15;
            Wt[k4 * 65 + h2] = Wv[h2 * K4 + c + k4];
        }
        __syncthreads();
#pragma unroll
        for (int k4 = 0; k4 < 16; ++k4) {
            float4 w = Wt[k4 * 65 + hh];
#pragma unroll
            for (int j = 0; j < 10; ++j) {
                float4 x = xs[(ng + 4 * j) * K4 + c + k4];
                acc[j].x += w.x * x.x;
                acc[j].y += w.y * x.y;
                acc[j].z += w.z * x.z;
                acc[j].w += w.w * x.w;
            }
        }
    }
#pragma unroll
    for (int j = 0; j < 10; ++j) {
        int node = base + ng + 4 * j;
        float v = acc[j].x + acc[j].y + acc[j].z + acc[j].w;
        if (HOUT) outh[node * HID + hh] = __float2half(v);
        else      outf[node * HID + hh] = v;
    }
}

// ---------------- GEMMs with piggybacked edge placement ----------------
#define GE_NB 2500
__global__ __launch_bounds__(256) void k_gemmedge(const int* __restrict__ ei,
                                                  int* fill, unsigned short* __restrict__ colp,
                                                  const float* __restrict__ x,
                                                  const float* __restrict__ W_in,
                                                  const float* __restrict__ W1,
                                                  float* __restrict__ h,
                                                  __half* __restrict__ g16) {
    __shared__ float4 Wt[16 * 65];
    __shared__ float4 xs[40 * 32];
    const int bid = blockIdx.x;
    const int t = threadIdx.x;

    // edge slice: issue atomics now, consume results after the GEMM
    const int ebase = bid * 320;
    int s1 = ei[ebase + t];
    int d1 = ei[N_EDGES + ebase + t];
    int k1 = atomicAdd(&fill[d1], 1);
    int s2 = 0, d2 = 0, k2 = MAXDEG;
    if (t < 64) {
        s2 = ei[ebase + 256 + t];
        d2 = ei[N_EDGES + ebase + 256 + t];
        k2 = atomicAdd(&fill[d2], 1);
    }

    if (bid < 1250)
        gemm_body<N_FEAT, false>(bid, x, W_in, h, nullptr, Wt, xs);
    else
        gemm_body<N_FEAT, true>(bid - 1250, x, W1, nullptr, g16, Wt, xs);

    // deferred stores: atomic results long since returned
    if (k1 < MAXDEG) colp[d1 * MAXDEG + k1] = (unsigned short)s1;
    if (k2 < MAXDEG) colp[d2 * MAXDEG + k2] = (unsigned short)s2;
}

// ---- fp16 row accumulate, scaled (FMA — same cost as plain add) ----
__device__ __forceinline__ void acc8s(const uint4 r, float* a, float s) {
    float2 f0 = __half22float2(*(const __half2*)&r.x);
    float2 f1 = __half22float2(*(const __half2*)&r.y);
    float2 f2 = __half22float2(*(const __half2*)&r.z);
    float2 f3 = __half22float2(*(const __half2*)&r.w);
    a[0] += s * f0.x; a[1] += s * f0.y; a[2] += s * f1.x; a[3] += s * f1.y;
    a[4] += s * f2.x; a[5] += s * f2.y; a[6] += s * f3.x; a[7] += s * f3.y;
}

// ------ fused gather(+BN/ReLU/res) [+ per-wave GEMM], TWO nodes per wave ------
// (R16 structure — empirically the chains-per-slot sweet spot; 4-node regressed.)
// 6250 blocks, 8 nodes/block, 2 independent gather chains per wave. Col
// prefetch: lanes 0-31 carry node A's cols, 32-63 node B's. Rare deg>32 via
// wave-uniform tail. Wave-decoupled (only barrier right after Wt staging).
// BN params folded: val = a*(di*sc) + base.
template <bool NSCALE, bool DOGEMM>
__global__ __launch_bounds__(256) void k_gather_fused(const __half* __restrict__ gin,
                                                      const unsigned short* __restrict__ colp,
                                                      const int* __restrict__ fill,
                                                      const float* __restrict__ b,
                                                      const float* __restrict__ gamma,
                                                      const float* __restrict__ beta,
                                                      const float* __restrict__ mean,
                                                      const float* __restrict__ var,
                                                      const float4* __restrict__ res4,
                                                      float4* __restrict__ h4,
                                                      const float* __restrict__ W,
                                                      __half* __restrict__ gout) {
    __shared__ float4 Wt[DOGEMM ? 16 * 65 : 1];
    __shared__ float4 hrow[DOGEMM ? 8 * 16 : 1];

    const int t = threadIdx.x;
    const int wv = t >> 6;
    const int lane = t & 63;
    const int hh8 = lane & 7;
    const int sub = lane >> 3;
    const int nA = blockIdx.x * 8 + wv * 2;
    const int nB = nA + 1;

    if (DOGEMM) {
        const float4* Wv = (const float4*)W;
        for (int i = t; i < HID * 16; i += 256) {
            int h2 = i >> 4, k4 = i & 15;
            Wt[k4 * 65 + h2] = Wv[i];
        }
        __syncthreads();   // only block barrier: Wt visible before any use
    }

    const uint4* gv = (const uint4*)gin;  // row = 8 x uint4 (128 B)
    int flA = fill[nA], flB = fill[nB];
    int degA = flA < MAXDEG ? flA : MAXDEG;
    int degB = flB < MAXDEG ? flB : MAXDEG;

    // col prefetch: lanes 0-31 -> A cols 0-31, lanes 32-63 -> B cols 0-31
    const int myn   = (lane < 32) ? nA : nB;
    const int myj   = lane & 31;
    const int mydeg = (lane < 32) ? degA : degB;
    const bool valid = (myj < mydeg);
    int call = valid ? (int)colp[myn * MAXDEG + myj] : myn;   // pad -> own row
    float sall;
    if (NSCALE) sall = valid ? rsqrtf((float)fill[call] + 1.0f) : 0.0f;
    else        sall = valid ? 1.0f : 0.0f;

    float aA[8], aB[8];
#pragma unroll
    for (int i = 0; i < 8; ++i) { aA[i] = 0.f; aB[i] = 0.f; }

    int dA32 = degA < 32 ? degA : 32;
    int dB32 = degB < 32 ? degB : 32;
    int nra = (dA32 + 7) >> 3;
    int nrb = (dB32 + 7) >> 3;
    int nr = nra > nrb ? nra : nrb;
#pragma unroll 4
    for (int r = 0; r < nr; ++r) {
        int j = r * 8 + sub;
        if (r < nra) {                                  // wave-uniform branch
            int c = __shfl(call, j);
            float s = __shfl(sall, j);
            acc8s(gv[c * 8 + hh8], aA, s);
        }
        if (r < nrb) {
            int c = __shfl(call, 32 + j);
            float s = __shfl(sall, 32 + j);
            acc8s(gv[c * 8 + hh8], aB, s);
        }
    }
    // rare overflow (deg > 32): wave-uniform tail, direct colp loads
    if (degA > 32) {
        for (int j = 32 + sub; j < degA; j += 8) {
            int c = (int)colp[nA * MAXDEG + j];
            float s = NSCALE ? rsqrtf((float)fill[c] + 1.0f) : 1.0f;
            acc8s(gv[c * 8 + hh8], aA, s);
        }
    }
    if (degB > 32) {
        for (int j = 32 + sub; j < degB; j += 8) {
            int c = (int)colp[nB * MAXDEG + j];
            float s = NSCALE ? rsqrtf((float)fill[c] + 1.0f) : 1.0f;
            acc8s(gv[c * 8 + hh8], aB, s);
        }
    }

#pragma unroll
    for (int m = 8; m <= 32; m <<= 1) {
#pragma unroll
        for (int i = 0; i < 8; ++i) { aA[i] += __shfl_xor(aA[i], m); aB[i] += __shfl_xor(aB[i], m); }
    }
    // allreduce complete: every lane holds the full 8-feature partials

    const float diA = rsqrtf((float)flA + 1.0f);
    const float diB = rsqrtf((float)flB + 1.0f);
    acc8s(gv[nA * 8 + hh8], aA, NSCALE ? diA : 1.0f);  // self loops
    acc8s(gv[nB * 8 + hh8], aB, NSCALE ? diB : 1.0f);

    // folded BN params: val = a*(di*sc) + base
    float sc[8], base8[8];
    {
        float4 b0 = ((const float4*)b)[hh8 * 2],     b1 = ((const float4*)b)[hh8 * 2 + 1];
        float4 g0 = ((const float4*)gamma)[hh8 * 2], g1 = ((const float4*)gamma)[hh8 * 2 + 1];
        float4 e0 = ((const float4*)beta)[hh8 * 2],  e1 = ((const float4*)beta)[hh8 * 2 + 1];
        float4 m0 = ((const float4*)mean)[hh8 * 2],  m1 = ((const float4*)mean)[hh8 * 2 + 1];
        float4 v0 = ((const float4*)var)[hh8 * 2],   v1 = ((const float4*)var)[hh8 * 2 + 1];
        float bb[8] = {b0.x, b0.y, b0.z, b0.w, b1.x, b1.y, b1.z, b1.w};
        float gg[8] = {g0.x, g0.y, g0.z, g0.w, g1.x, g1.y, g1.z, g1.w};
        float ee[8] = {e0.x, e0.y, e0.z, e0.w, e1.x, e1.y, e1.z, e1.w};
        float mm[8] = {m0.x, m0.y, m0.z, m0.w, m1.x, m1.y, m1.z, m1.w};
        float vv[8] = {v0.x, v0.y, v0.z, v0.w, v1.x, v1.y, v1.z, v1.w};
#pragma unroll
        for (int k = 0; k < 8; ++k) {
            sc[k] = gg[k] * rsqrtf(vv[k] + BN_EPS);
            base8[k] = (bb[k] - mm[k]) * sc[k] + ee[k];
        }
    }

    float oA[8], oB[8];
#pragma unroll
    for (int i = 0; i < 8; ++i) {
        oA[i] = fmaxf(aA[i] * (diA * sc[i]) + base8[i], 0.f);
        oB[i] = fmaxf(aB[i] * (diB * sc[i]) + base8[i], 0.f);
    }
    if (res4) {
        float4 rA0 = res4[nA * 16 + hh8 * 2], rA1 = res4[nA * 16 + hh8 * 2 + 1];
        float4 rB0 = res4[nB * 16 + hh8 * 2], rB1 = res4[nB * 16 + hh8 * 2 + 1];
        oA[0] += rA0.x; oA[1] += rA0.y; oA[2] += rA0.z; oA[3] += rA0.w;
        oA[4] += rA1.x; oA[5] += rA1.y; oA[6] += rA1.z; oA[7] += rA1.w;
        oB[0] += rB0.x; oB[1] += rB0.y; oB[2] += rB0.z; oB[3] += rB0.w;
        oB[4] += rB1.x; oB[5] += rB1.y; oB[6] += rB1.z; oB[7] += rB1.w;
    }
    float4 loA = make_float4(oA[0], oA[1], oA[2], oA[3]);
    float4 hiA = make_float4(oA[4], oA[5], oA[6], oA[7]);
    float4 loB = make_float4(oB[0], oB[1], oB[2], oB[3]);
    float4 hiB = make_float4(oB[4], oB[5], oB[6], oB[7]);
    if (sub == 0) {
        h4[nA * 16 + hh8 * 2]     = loA;
        h4[nA * 16 + hh8 * 2 + 1] = hiA;
        h4[nB * 16 + hh8 * 2]     = loB;
        h4[nB * 16 + hh8 * 2 + 1] = hiB;
        if (DOGEMM) {
            hrow[(wv * 2) * 16 + hh8 * 2]         = loA;
            hrow[(wv * 2) * 16 + hh8 * 2 + 1]     = hiA;
            hrow[(wv * 2 + 1) * 16 + hh8 * 2]     = loB;
            hrow[(wv * 2 + 1) * 16 + hh8 * 2 + 1] = hiB;
        }
    }

    if (DOGEMM) {
        // same-wave LDS write->read: in-order, no barrier needed
        const int hh = lane;
        float4 accA = make_float4(0.f, 0.f, 0.f, 0.f);
        float4 accB = make_float4(0.f, 0.f, 0.f, 0.f);
#pragma unroll
        for (int k4 = 0; k4 < 16; ++k4) {
            float4 w = Wt[k4 * 65 + hh];
            float4 hA = hrow[(wv * 2) * 16 + k4];      // wave-broadcast (free)
            float4 hB = hrow[(wv * 2 + 1) * 16 + k4];
            accA.x += hA.x * w.x; accA.y += hA.y * w.y;
            accA.z += hA.z * w.z; accA.w += hA.w * w.w;
            accB.x += hB.x * w.x; accB.y += hB.y * w.y;
            accB.z += hB.z * w.z; accB.w += hB.w * w.w;
        }
        gout[nA * HID + hh] = __float2half((accA.x + accA.y + accA.z + accA.w) * diA);
        gout[nB * HID + hh] = __float2half((accB.x + accB.y + accB.z + accB.w) * diB);
    }
}

// ---------------- pool + final linear: one 1024-thread block per graph ----------------
__device__ __forceinline__ int lowerb(const int* __restrict__ b, int val) {
    int lo = 0, hi = N_NODES;
    while (lo < hi) {
        int mid = (lo + hi) >> 1;
        if (b[mid] < val) lo = mid + 1; else hi = mid;
    }
    return lo;
}

__global__ __launch_bounds__(1024) void k_poolfinal(const float* __restrict__ h,
                                                    const int* __restrict__ batch,
                                                    const float* __restrict__ lin_w,
                                                    const float* __restrict__ lin_b,
                                                    float* __restrict__ out) {
    __shared__ float red[16][HID];
    int g = blockIdx.x;
    int w = threadIdx.x >> 6;
    int hh = threadIdx.x & 63;
    int start = lowerb(batch, g);
    int end = lowerb(batch, g + 1);
    int len = end - start;
    float acc = 0.f;
    for (int n = start + w; n < end; n += 16) acc += h[n * HID + hh];
    red[w][hh] = acc;
    __syncthreads();
    if (w == 0) {
        float s = 0.f;
#pragma unroll
        for (int i = 0; i < 16; ++i) s += red[i][hh];
        float c = fmaxf((float)len, 1.0f);
        float v = (s / c) * lin_w[hh];
#pragma unroll
        for (int off = 32; off > 0; off >>= 1) v += __shfl_down(v, off);
        if (hh == 0) out[g] = v + lin_b[0];
    }
}

extern "C" void kernel_launch(void* const* d_in, const int* in_sizes, int n_in,
                              void* d_out, int out_size, void* d_ws, size_t ws_size,
                              hipStream_t stream) {
    const float* x     = (const float*)d_in[0];
    const int*   ei    = (const int*)d_in[1];
    const int*   batch = (const int*)d_in[2];
    const float* W_in  = (const float*)d_in[3];
    const float* W1    = (const float*)d_in[4];
    const float* b1    = (const float*)d_in[5];
    const float* Ws    = (const float*)d_in[6];
    const float* bs_   = (const float*)d_in[7];
    const float* bn_g  = (const float*)d_in[8];
    const float* bn_b  = (const float*)d_in[9];
    const float* bn_m  = (const float*)d_in[10];
    const float* bn_v  = (const float*)d_in[11];
    const float* lin_w = (const float*)d_in[12];
    const float* lin_b = (const float*)d_in[13];
    float* out = (float*)d_out;

    char* q = (char*)d_ws;
    int*            fill = (int*)q;             q += (size_t)50048 * 4;
    unsigned short* colp = (unsigned short*)q;  q += (size_t)N_NODES * MAXDEG * 2;
    __half*         g16a = (__half*)q;          q += (size_t)N_NODES * HID * 2;
    __half*         g16b = (__half*)q;          q += (size_t)N_NODES * HID * 2;
    float*          h    = (float*)q;           q += (size_t)N_NODES * HID * 4;

    const int NB_GA2 = N_NODES / 8;  // 6250
    float4* h4 = (float4*)h;

    // zero fill via memset node (capture-safe), then fat gemm+edge dispatch
    hipMemsetAsync(fill, 0, (size_t)N_NODES * 4, stream);
    k_gemmedge<<<GE_NB, 256, 0, stream>>>(ei, fill, colp, x, W_in, W1, h, g16a);

    // layer 1: gather (per-source dinv; g16a unscaled) + fused gemm for layer 2
    k_gather_fused<true, true><<<NB_GA2, 256, 0, stream>>>(
        g16a, colp, fill, b1, bn_g, bn_b, bn_m, bn_v,
        (const float4*)h, h4, Ws + 0 * HID * HID, g16b);

    // layers 2-4: gather (pre-scaled g16) + fused gemm for next layer
    k_gather_fused<false, true><<<NB_GA2, 256, 0, stream>>>(
        g16b, colp, fill, bs_ + 0 * HID,
        bn_g + 1 * HID, bn_b + 1 * HID, bn_m + 1 * HID, bn_v + 1 * HID,
        (const float4*)h, h4, Ws + 1 * HID * HID, g16a);

    k_gather_fused<false, true><<<NB_GA2, 256, 0, stream>>>(
        g16a, colp, fill, bs_ + 1 * HID,
        bn_g + 2 * HID, bn_b + 2 * HID, bn_m + 2 * HID, bn_v + 2 * HID,
        (const float4*)h, h4, Ws + 2 * HID * HID, g16b);

    k_gather_fused<false, true><<<NB_GA2, 256, 0, stream>>>(
        g16b, colp, fill, bs_ + 2 * HID,
        bn_g + 3 * HID, bn_b + 3 * HID, bn_m + 3 * HID, bn_v + 3 * HID,
        (const float4*)h, h4, Ws + 3 * HID * HID, g16a);

    // layer 5: gather only (no residual, no next gemm)
    k_gather_fused<false, false><<<NB_GA2, 256, 0, stream>>>(
        g16a, colp, fill, bs_ + 3 * HID,
        bn_g + 4 * HID, bn_b + 4 * HID, bn_m + 4 * HID, bn_v + 4 * HID,
        nullptr, h4, nullptr, nullptr);

    // pool + final
    k_poolfinal<<<N_GRAPHS, 1024, 0, stream>>>(h, batch, lin_w, lin_b, out);
}